// Round 1
// baseline (556.352 us; speedup 1.0000x reference)
//
#include <hip/hip_runtime.h>
#include <hip/hip_bf16.h>
#include <stdint.h>

#define T_TOK 4096
#define DIM   1024
#define HID   2048
#define NE    8

typedef unsigned short ushort_t;
typedef __attribute__((ext_vector_type(8))) short bf16x8;
typedef __attribute__((ext_vector_type(4))) float f32x4;

__device__ __forceinline__ unsigned short f2bf(float f) {
  unsigned u = __float_as_uint(f);
  unsigned r = (u + 0x7fffu + ((u >> 16) & 1u)) >> 16;
  return (unsigned short)r;
}

__device__ __forceinline__ void gl2lds16(const ushort_t* g, ushort_t* l) {
  void* gv = (void*)g;
  __builtin_amdgcn_global_load_lds((__attribute__((address_space(1))) void*)gv,
                                   (__attribute__((address_space(3))) void*)l,
                                   16, 0, 0);
}

// ---------------- router: logits, top-2, gates, compaction ----------------
__global__ void router_kernel(const float* __restrict__ x, const float* __restrict__ Wr,
                              int* __restrict__ cnt, int* __restrict__ tok,
                              float* __restrict__ gate) {
  const int wave = threadIdx.x >> 6;
  const int lane = threadIdx.x & 63;
  const int t = blockIdx.x * 4 + wave;
  float acc[NE];
#pragma unroll
  for (int e = 0; e < NE; e++) acc[e] = 0.f;
  const float* xr = x + (size_t)t * DIM;
  for (int d = lane; d < DIM; d += 64) {
    float xv = xr[d];
    const float* wr = Wr + (size_t)d * NE;
#pragma unroll
    for (int e = 0; e < NE; e++) acc[e] += xv * wr[e];
  }
#pragma unroll
  for (int off = 32; off >= 1; off >>= 1) {
#pragma unroll
    for (int e = 0; e < NE; e++) acc[e] += __shfl_xor(acc[e], off, 64);
  }
  if (lane == 0) {
    int i1 = 0;
#pragma unroll
    for (int e = 1; e < NE; e++) if (acc[e] > acc[i1]) i1 = e;
    int i2 = (i1 == 0) ? 1 : 0;
#pragma unroll
    for (int e = 0; e < NE; e++) {
      if (e == i1) continue;
      if (acc[e] > acc[i2]) i2 = e;
    }
    float r = expf(acc[i2] - acc[i1]);   // p2/p1
    float g1 = 1.f / (1.f + r);
    float g2 = 1.f - g1;
    int p;
    p = atomicAdd(&cnt[i1], 1); tok[i1 * T_TOK + p] = t; gate[i1 * T_TOK + p] = g1;
    p = atomicAdd(&cnt[i2], 1); tok[i2 * T_TOK + p] = t; gate[i2 * T_TOK + p] = g2;
  }
}

__global__ void prefix_kernel(const int* __restrict__ cnt, int* __restrict__ base) {
  if (threadIdx.x == 0) {
    int s = 0;
    for (int e = 0; e < NE; e++) { base[e] = s; s += cnt[e]; }
  }
}

// ---------------- fp32 -> bf16 straight convert (x) ----------------
__global__ void convert_x_kernel(const float* __restrict__ x, ushort_t* __restrict__ xb) {
  int i = blockIdx.x * 256 + threadIdx.x;
  float4 v = ((const float4*)x)[i];
  ushort4 o;
  o.x = f2bf(v.x); o.y = f2bf(v.y); o.z = f2bf(v.z); o.w = f2bf(v.w);
  ((ushort4*)xb)[i] = o;
}

// -------- per-expert transpose + convert: src fp32 [R][C] -> dst bf16 [C][R] --------
__global__ void transpose_convert(const float* __restrict__ src, ushort_t* __restrict__ dst,
                                  int R, int C) {
  __shared__ float lds[64][65];
  const int e = blockIdx.z;
  const float* s = src + (size_t)e * R * C;
  ushort_t* d = dst + (size_t)e * R * C;
  const int c0 = blockIdx.x * 64, r0 = blockIdx.y * 64;
  const int tid = threadIdx.x;
#pragma unroll
  for (int p = 0; p < 4; p++) {
    int idx = p * 256 + tid;            // 0..1023
    int r = idx >> 4, c4 = idx & 15;
    float4 v = *(const float4*)(s + (size_t)(r0 + r) * C + c0 + c4 * 4);
    lds[r][c4 * 4 + 0] = v.x; lds[r][c4 * 4 + 1] = v.y;
    lds[r][c4 * 4 + 2] = v.z; lds[r][c4 * 4 + 3] = v.w;
  }
  __syncthreads();
#pragma unroll
  for (int p = 0; p < 4; p++) {
    int idx = p * 256 + tid;
    int cc = idx >> 4, r4 = idx & 15;
    ushort4 o;
    o.x = f2bf(lds[r4 * 4 + 0][cc]);
    o.y = f2bf(lds[r4 * 4 + 1][cc]);
    o.z = f2bf(lds[r4 * 4 + 2][cc]);
    o.w = f2bf(lds[r4 * 4 + 3][cc]);
    *(ushort4*)(d + (size_t)(c0 + cc) * R + r0 + r4 * 4) = o;
  }
}

// ---------------- GEMM1: h = silu(x@W1) * (x@W3), gathered rows ----------------
// A: xb gathered token rows [128 x K=1024]; B: w1t/w3t [H][D] rows (k-contig), 64-wide tile
__global__ __launch_bounds__(256, 2)
void gemm1_kernel(const ushort_t* __restrict__ xb,
                  const ushort_t* __restrict__ w1t,
                  const ushort_t* __restrict__ w3t,
                  const int* __restrict__ tok,
                  const int* __restrict__ cnt,
                  const int* __restrict__ base,
                  ushort_t* __restrict__ hbuf) {
  const int e = blockIdx.z;
  const int mt = blockIdx.y;
  const int nt = blockIdx.x;
  const int Ne = cnt[e];
  if (mt * 128 >= Ne) return;

  __shared__ __attribute__((aligned(16))) ushort_t lA[128 * 32];
  __shared__ __attribute__((aligned(16))) ushort_t lB1[64 * 32];
  __shared__ __attribute__((aligned(16))) ushort_t lB3[64 * 32];

  const int tid = threadIdx.x;
  const int lane = tid & 63;
  const int wave = tid >> 6;

  // staging addresses (chunk = 16B = 8 bf16; XOR-swizzled k-chunk within row)
  const int r1 = tid >> 2;
  const int r2 = r1 + 64;
  const int row1 = mt * 128 + r1;
  const int row2 = mt * 128 + r2;
  const int t1 = (row1 < Ne) ? tok[e * T_TOK + row1] : 0;
  const int t2 = (row2 < Ne) ? tok[e * T_TOK + row2] : 0;
  const int kc1 = (tid & 3) ^ ((r1 >> 1) & 3);
  const int kc2 = (tid & 3) ^ ((r2 >> 1) & 3);
  const ushort_t* gA1 = xb + (size_t)t1 * DIM + kc1 * 8;
  const ushort_t* gA2 = xb + (size_t)t2 * DIM + kc2 * 8;

  const int nb = tid >> 2;
  const int kcb = (tid & 3) ^ ((nb >> 1) & 3);
  const int h0 = nt * 64;
  const ushort_t* gB1 = w1t + ((size_t)e * HID + h0 + nb) * DIM + kcb * 8;
  const ushort_t* gB3 = w3t + ((size_t)e * HID + h0 + nb) * DIM + kcb * 8;

  ushort_t* dA1 = lA + tid * 8;
  ushort_t* dA2 = lA + (tid + 256) * 8;
  ushort_t* dB1 = lB1 + tid * 8;
  ushort_t* dB3 = lB3 + tid * 8;

  f32x4 c1[4][2], c3[4][2];
#pragma unroll
  for (int i = 0; i < 4; i++)
#pragma unroll
    for (int j = 0; j < 2; j++) {
      c1[i][j] = (f32x4){0.f, 0.f, 0.f, 0.f};
      c3[i][j] = (f32x4){0.f, 0.f, 0.f, 0.f};
    }

  const int wm = (wave >> 1) * 64;
  const int wn = (wave & 1) * 32;
  const int m = lane & 15;
  const int kq = lane >> 4;

  int aOff[4], bOff[2];
#pragma unroll
  for (int i = 0; i < 4; i++) {
    int r = wm + i * 16 + m;
    aOff[i] = (r * 4 + (kq ^ ((r >> 1) & 3))) * 8;
  }
#pragma unroll
  for (int j = 0; j < 2; j++) {
    int n = wn + j * 16 + m;
    bOff[j] = (n * 4 + (kq ^ ((n >> 1) & 3))) * 8;
  }

  for (int k0 = 0; k0 < DIM; k0 += 32) {
    gl2lds16(gA1 + k0, dA1);
    gl2lds16(gA2 + k0, dA2);
    gl2lds16(gB1 + k0, dB1);
    gl2lds16(gB3 + k0, dB3);
    __syncthreads();
    bf16x8 a[4], b1f[2], b3f[2];
#pragma unroll
    for (int i = 0; i < 4; i++) a[i] = *(const bf16x8*)(lA + aOff[i]);
#pragma unroll
    for (int j = 0; j < 2; j++) {
      b1f[j] = *(const bf16x8*)(lB1 + bOff[j]);
      b3f[j] = *(const bf16x8*)(lB3 + bOff[j]);
    }
#pragma unroll
    for (int i = 0; i < 4; i++)
#pragma unroll
      for (int j = 0; j < 2; j++) {
        c1[i][j] = __builtin_amdgcn_mfma_f32_16x16x32_bf16(a[i], b1f[j], c1[i][j], 0, 0, 0);
        c3[i][j] = __builtin_amdgcn_mfma_f32_16x16x32_bf16(a[i], b3f[j], c3[i][j], 0, 0, 0);
      }
    __syncthreads();
  }

  const int be = base[e];
  const int m4 = lane >> 4;
#pragma unroll
  for (int i = 0; i < 4; i++) {
#pragma unroll
    for (int j = 0; j < 2; j++) {
      int hcol = h0 + wn + j * 16 + m;
#pragma unroll
      for (int reg = 0; reg < 4; reg++) {
        int rowg = mt * 128 + wm + i * 16 + m4 * 4 + reg;
        if (rowg < Ne) {
          float v1 = c1[i][j][reg];
          float v3 = c3[i][j][reg];
          float hv = (v1 / (1.f + expf(-v1))) * v3;   // silu(v1)*v3
          hbuf[(size_t)(be + rowg) * HID + hcol] = f2bf(hv);
        }
      }
    }
  }
}

// ---------------- GEMM2: out[tok] += gate * (h @ W2) ----------------
__global__ __launch_bounds__(256, 2)
void gemm2_kernel(const ushort_t* __restrict__ hbuf,
                  const ushort_t* __restrict__ w2t,
                  const int* __restrict__ tok,
                  const float* __restrict__ gates,
                  const int* __restrict__ cnt,
                  const int* __restrict__ base,
                  float* __restrict__ out) {
  const int e = blockIdx.z;
  const int mt = blockIdx.y;
  const int nt = blockIdx.x;
  const int Ne = cnt[e];
  if (mt * 128 >= Ne) return;
  const int be = base[e];

  __shared__ __attribute__((aligned(16))) ushort_t lA[128 * 32];
  __shared__ __attribute__((aligned(16))) ushort_t lB[64 * 32];

  const int tid = threadIdx.x;
  const int lane = tid & 63;
  const int wave = tid >> 6;

  const int r1 = tid >> 2;
  const int r2 = r1 + 64;
  const int rr1 = min(mt * 128 + r1, Ne - 1);
  const int rr2 = min(mt * 128 + r2, Ne - 1);
  const int kc1 = (tid & 3) ^ ((r1 >> 1) & 3);
  const int kc2 = (tid & 3) ^ ((r2 >> 1) & 3);
  const ushort_t* gA1 = hbuf + (size_t)(be + rr1) * HID + kc1 * 8;
  const ushort_t* gA2 = hbuf + (size_t)(be + rr2) * HID + kc2 * 8;

  const int nb = tid >> 2;
  const int kcb = (tid & 3) ^ ((nb >> 1) & 3);
  const int d0 = nt * 64;
  const ushort_t* gB = w2t + ((size_t)e * DIM + d0 + nb) * HID + kcb * 8;

  ushort_t* dA1 = lA + tid * 8;
  ushort_t* dA2 = lA + (tid + 256) * 8;
  ushort_t* dB = lB + tid * 8;

  f32x4 c[4][2];
#pragma unroll
  for (int i = 0; i < 4; i++)
#pragma unroll
    for (int j = 0; j < 2; j++) c[i][j] = (f32x4){0.f, 0.f, 0.f, 0.f};

  const int wm = (wave >> 1) * 64;
  const int wn = (wave & 1) * 32;
  const int m = lane & 15;
  const int kq = lane >> 4;

  int aOff[4], bOff[2];
#pragma unroll
  for (int i = 0; i < 4; i++) {
    int r = wm + i * 16 + m;
    aOff[i] = (r * 4 + (kq ^ ((r >> 1) & 3))) * 8;
  }
#pragma unroll
  for (int j = 0; j < 2; j++) {
    int n = wn + j * 16 + m;
    bOff[j] = (n * 4 + (kq ^ ((n >> 1) & 3))) * 8;
  }

  for (int k0 = 0; k0 < HID; k0 += 32) {
    gl2lds16(gA1 + k0, dA1);
    gl2lds16(gA2 + k0, dA2);
    gl2lds16(gB + k0, dB);
    __syncthreads();
    bf16x8 a[4], bf[2];
#pragma unroll
    for (int i = 0; i < 4; i++) a[i] = *(const bf16x8*)(lA + aOff[i]);
#pragma unroll
    for (int j = 0; j < 2; j++) bf[j] = *(const bf16x8*)(lB + bOff[j]);
#pragma unroll
    for (int i = 0; i < 4; i++)
#pragma unroll
      for (int j = 0; j < 2; j++)
        c[i][j] = __builtin_amdgcn_mfma_f32_16x16x32_bf16(a[i], bf[j], c[i][j], 0, 0, 0);
    __syncthreads();
  }

  const int m4 = lane >> 4;
#pragma unroll
  for (int i = 0; i < 4; i++) {
#pragma unroll
    for (int j = 0; j < 2; j++) {
      int dcol = d0 + wn + j * 16 + m;
#pragma unroll
      for (int reg = 0; reg < 4; reg++) {
        int rowg = mt * 128 + wm + i * 16 + m4 * 4 + reg;
        if (rowg < Ne) {
          int t = tok[e * T_TOK + rowg];
          float g = gates[e * T_TOK + rowg];
          atomicAdd(out + (size_t)t * DIM + dcol, g * c[i][j][reg]);
        }
      }
    }
  }
}

extern "C" void kernel_launch(void* const* d_in, const int* in_sizes, int n_in,
                              void* d_out, int out_size, void* d_ws, size_t ws_size,
                              hipStream_t stream) {
  (void)in_sizes; (void)n_in; (void)ws_size;
  const float* x  = (const float*)d_in[0];
  const float* Wr = (const float*)d_in[1];
  const float* W1 = (const float*)d_in[2];
  const float* W2 = (const float*)d_in[3];
  const float* W3 = (const float*)d_in[4];
  float* out = (float*)d_out;

  char* w = (char*)d_ws;
  ushort_t* xb   = (ushort_t*)w; w += (size_t)T_TOK * DIM * 2;       //   8 MB
  ushort_t* w1t  = (ushort_t*)w; w += (size_t)NE * DIM * HID * 2;    //  33.5 MB
  ushort_t* w3t  = (ushort_t*)w; w += (size_t)NE * DIM * HID * 2;    //  33.5 MB
  ushort_t* w2t  = (ushort_t*)w; w += (size_t)NE * HID * DIM * 2;    //  33.5 MB
  ushort_t* hbuf = (ushort_t*)w; w += (size_t)2 * T_TOK * HID * 2;   //  33.5 MB
  int*   tok   = (int*)w;   w += (size_t)NE * T_TOK * 4;
  float* gates = (float*)w; w += (size_t)NE * T_TOK * 4;
  int*   cnt   = (int*)w;   w += 128;
  int*   base  = (int*)w;   w += 128;

  hipMemsetAsync(d_out, 0, (size_t)out_size * sizeof(float), stream);
  hipMemsetAsync(cnt, 0, 128, stream);

  convert_x_kernel<<<T_TOK * DIM / 1024, 256, 0, stream>>>(x, xb);
  transpose_convert<<<dim3(HID / 64, DIM / 64, NE), 256, 0, stream>>>(W1, w1t, DIM, HID);
  transpose_convert<<<dim3(HID / 64, DIM / 64, NE), 256, 0, stream>>>(W3, w3t, DIM, HID);
  transpose_convert<<<dim3(DIM / 64, HID / 64, NE), 256, 0, stream>>>(W2, w2t, HID, DIM);
  router_kernel<<<T_TOK / 4, 256, 0, stream>>>(x, Wr, cnt, tok, gates);
  prefix_kernel<<<1, 64, 0, stream>>>(cnt, base);
  gemm1_kernel<<<dim3(HID / 64, 32, NE), 256, 0, stream>>>(xb, w1t, w3t, tok, cnt, base, hbuf);
  gemm2_kernel<<<dim3(DIM / 64, 32, NE), 256, 0, stream>>>(hbuf, w2t, tok, gates, cnt, base, out);
}

// Round 2
// 534.488 us; speedup vs baseline: 1.0409x; 1.0409x over previous
//
#include <hip/hip_runtime.h>
#include <hip/hip_bf16.h>
#include <stdint.h>

#define T_TOK 4096
#define DIM   1024
#define HID   2048
#define NE    8

typedef unsigned short ushort_t;
typedef __attribute__((ext_vector_type(8))) short bf16x8;
typedef __attribute__((ext_vector_type(4))) float f32x4;

__device__ __forceinline__ unsigned short f2bf(float f) {
  unsigned u = __float_as_uint(f);
  unsigned r = (u + 0x7fffu + ((u >> 16) & 1u)) >> 16;
  return (unsigned short)r;
}

__device__ __forceinline__ void gl2lds16(const ushort_t* g, ushort_t* l) {
  void* gv = (void*)g;
  __builtin_amdgcn_global_load_lds((__attribute__((address_space(1))) void*)gv,
                                   (__attribute__((address_space(3))) void*)l,
                                   16, 0, 0);
}

// ---------------- router: logits, top-2, gates, compaction ----------------
__global__ void router_kernel(const float* __restrict__ x, const float* __restrict__ Wr,
                              int* __restrict__ cnt, int* __restrict__ tok,
                              float* __restrict__ gate) {
  const int wave = threadIdx.x >> 6;
  const int lane = threadIdx.x & 63;
  const int t = blockIdx.x * 4 + wave;
  float acc[NE];
#pragma unroll
  for (int e = 0; e < NE; e++) acc[e] = 0.f;
  const float* xr = x + (size_t)t * DIM;
  for (int d = lane; d < DIM; d += 64) {
    float xv = xr[d];
    const float* wr = Wr + (size_t)d * NE;
#pragma unroll
    for (int e = 0; e < NE; e++) acc[e] += xv * wr[e];
  }
#pragma unroll
  for (int off = 32; off >= 1; off >>= 1) {
#pragma unroll
    for (int e = 0; e < NE; e++) acc[e] += __shfl_xor(acc[e], off, 64);
  }
  if (lane == 0) {
    int i1 = 0;
#pragma unroll
    for (int e = 1; e < NE; e++) if (acc[e] > acc[i1]) i1 = e;
    int i2 = (i1 == 0) ? 1 : 0;
#pragma unroll
    for (int e = 0; e < NE; e++) {
      if (e == i1) continue;
      if (acc[e] > acc[i2]) i2 = e;
    }
    float r = expf(acc[i2] - acc[i1]);   // p2/p1
    float g1 = 1.f / (1.f + r);
    float g2 = 1.f - g1;
    int p;
    p = atomicAdd(&cnt[i1], 1); tok[i1 * T_TOK + p] = t; gate[i1 * T_TOK + p] = g1;
    p = atomicAdd(&cnt[i2], 1); tok[i2 * T_TOK + p] = t; gate[i2 * T_TOK + p] = g2;
  }
}

__global__ void prefix_kernel(const int* __restrict__ cnt, int* __restrict__ base) {
  if (threadIdx.x == 0) {
    int s = 0;
    for (int e = 0; e < NE; e++) { base[e] = s; s += cnt[e]; }
  }
}

// ---------------- fp32 -> bf16 straight convert (x) ----------------
__global__ void convert_x_kernel(const float* __restrict__ x, ushort_t* __restrict__ xb) {
  int i = blockIdx.x * 256 + threadIdx.x;
  float4 v = ((const float4*)x)[i];
  ushort4 o;
  o.x = f2bf(v.x); o.y = f2bf(v.y); o.z = f2bf(v.z); o.w = f2bf(v.w);
  ((ushort4*)xb)[i] = o;
}

// -------- per-expert transpose + convert: src fp32 [R][C] -> dst bf16 [C][R] --------
__global__ void transpose_convert(const float* __restrict__ src, ushort_t* __restrict__ dst,
                                  int R, int C) {
  __shared__ float lds[64][65];
  const int e = blockIdx.z;
  const float* s = src + (size_t)e * R * C;
  ushort_t* d = dst + (size_t)e * R * C;
  const int c0 = blockIdx.x * 64, r0 = blockIdx.y * 64;
  const int tid = threadIdx.x;
#pragma unroll
  for (int p = 0; p < 4; p++) {
    int idx = p * 256 + tid;            // 0..1023
    int r = idx >> 4, c4 = idx & 15;
    float4 v = *(const float4*)(s + (size_t)(r0 + r) * C + c0 + c4 * 4);
    lds[r][c4 * 4 + 0] = v.x; lds[r][c4 * 4 + 1] = v.y;
    lds[r][c4 * 4 + 2] = v.z; lds[r][c4 * 4 + 3] = v.w;
  }
  __syncthreads();
#pragma unroll
  for (int p = 0; p < 4; p++) {
    int idx = p * 256 + tid;
    int cc = idx >> 4, r4 = idx & 15;
    ushort4 o;
    o.x = f2bf(lds[r4 * 4 + 0][cc]);
    o.y = f2bf(lds[r4 * 4 + 1][cc]);
    o.z = f2bf(lds[r4 * 4 + 2][cc]);
    o.w = f2bf(lds[r4 * 4 + 3][cc]);
    *(ushort4*)(d + (size_t)(c0 + cc) * R + r0 + r4 * 4) = o;
  }
}

// ---------------- GEMM1: h = gate * silu(x@W1) * (x@W3), gathered rows ----------------
// A: xb gathered token rows [128 x K=1024]; B: w1t/w3t [H][D] rows (k-contig), 64-wide tile
// 16 MFMA per wave per K-step (4m x 2n x {W1,W3})
__global__ __launch_bounds__(256, 2)
void gemm1_kernel(const ushort_t* __restrict__ xb,
                  const ushort_t* __restrict__ w1t,
                  const ushort_t* __restrict__ w3t,
                  const int* __restrict__ tok,
                  const float* __restrict__ gates,
                  const int* __restrict__ cnt,
                  const int* __restrict__ base,
                  ushort_t* __restrict__ hbuf) {
  const int e = blockIdx.z;
  const int mt = blockIdx.y;
  const int nt = blockIdx.x;
  const int Ne = cnt[e];
  if (mt * 128 >= Ne) return;

  __shared__ __attribute__((aligned(16))) ushort_t lA[128 * 32];
  __shared__ __attribute__((aligned(16))) ushort_t lB1[64 * 32];
  __shared__ __attribute__((aligned(16))) ushort_t lB3[64 * 32];

  const int tid = threadIdx.x;
  const int lane = tid & 63;
  const int wave = tid >> 6;

  // staging addresses (chunk = 16B = 8 bf16; XOR-swizzled k-chunk within row)
  const int r1 = tid >> 2;
  const int row1 = mt * 128 + r1;
  const int row2 = row1 + 64;
  const int t1 = (row1 < Ne) ? tok[e * T_TOK + row1] : 0;
  const int t2 = (row2 < Ne) ? tok[e * T_TOK + row2] : 0;
  const int kc = (tid & 3) ^ ((r1 >> 1) & 3);   // (r1+64)>>1 has same low bits
  const ushort_t* gA1 = xb + (size_t)t1 * DIM + kc * 8;
  const ushort_t* gA2 = xb + (size_t)t2 * DIM + kc * 8;

  const int h0 = nt * 64;
  const ushort_t* gB1 = w1t + ((size_t)e * HID + h0 + r1) * DIM + kc * 8;
  const ushort_t* gB3 = w3t + ((size_t)e * HID + h0 + r1) * DIM + kc * 8;

  ushort_t* dA1 = lA + tid * 8;
  ushort_t* dA2 = lA + (tid + 256) * 8;
  ushort_t* dB1 = lB1 + tid * 8;
  ushort_t* dB3 = lB3 + tid * 8;

  f32x4 c1[4][2], c3[4][2];
#pragma unroll
  for (int i = 0; i < 4; i++)
#pragma unroll
    for (int j = 0; j < 2; j++) {
      c1[i][j] = (f32x4){0.f, 0.f, 0.f, 0.f};
      c3[i][j] = (f32x4){0.f, 0.f, 0.f, 0.f};
    }

  const int wm = (wave >> 1) * 64;
  const int wn = (wave & 1) * 32;
  const int m = lane & 15;
  const int kq = lane >> 4;

  int aOff[4], bOff[2];
#pragma unroll
  for (int i = 0; i < 4; i++) {
    int r = wm + i * 16 + m;
    aOff[i] = (r * 4 + (kq ^ ((r >> 1) & 3))) * 8;
  }
#pragma unroll
  for (int j = 0; j < 2; j++) {
    int n = wn + j * 16 + m;
    bOff[j] = (n * 4 + (kq ^ ((n >> 1) & 3))) * 8;
  }

  for (int k0 = 0; k0 < DIM; k0 += 32) {
    gl2lds16(gA1 + k0, dA1);
    gl2lds16(gA2 + k0, dA2);
    gl2lds16(gB1 + k0, dB1);
    gl2lds16(gB3 + k0, dB3);
    __syncthreads();
    bf16x8 a[4], b1f[2], b3f[2];
#pragma unroll
    for (int i = 0; i < 4; i++) a[i] = *(const bf16x8*)(lA + aOff[i]);
#pragma unroll
    for (int j = 0; j < 2; j++) {
      b1f[j] = *(const bf16x8*)(lB1 + bOff[j]);
      b3f[j] = *(const bf16x8*)(lB3 + bOff[j]);
    }
#pragma unroll
    for (int i = 0; i < 4; i++)
#pragma unroll
      for (int j = 0; j < 2; j++) {
        c1[i][j] = __builtin_amdgcn_mfma_f32_16x16x32_bf16(a[i], b1f[j], c1[i][j], 0, 0, 0);
        c3[i][j] = __builtin_amdgcn_mfma_f32_16x16x32_bf16(a[i], b3f[j], c3[i][j], 0, 0, 0);
      }
    __syncthreads();
  }

  const int be = base[e];
  const int m4 = lane >> 4;
#pragma unroll
  for (int i = 0; i < 4; i++) {
#pragma unroll
    for (int j = 0; j < 2; j++) {
      int hcol = h0 + wn + j * 16 + m;
#pragma unroll
      for (int reg = 0; reg < 4; reg++) {
        int rowg = mt * 128 + wm + i * 16 + m4 * 4 + reg;
        if (rowg < Ne) {
          float v1 = c1[i][j][reg];
          float v3 = c3[i][j][reg];
          float g = gates[e * T_TOK + rowg];
          float hv = g * (v1 / (1.f + expf(-v1))) * v3;   // gate*silu(v1)*v3
          hbuf[(size_t)(be + rowg) * HID + hcol] = f2bf(hv);
        }
      }
    }
  }
}

// ---------------- GEMM2: out[tok] += h @ W2   (gate pre-applied in hbuf) ----------------
// 128x128 tile, 4 waves x (64x64), 16 MFMA per wave per K-step
__global__ __launch_bounds__(256, 2)
void gemm2_kernel(const ushort_t* __restrict__ hbuf,
                  const ushort_t* __restrict__ w2t,
                  const int* __restrict__ tok,
                  const int* __restrict__ cnt,
                  const int* __restrict__ base,
                  float* __restrict__ out) {
  const int e = blockIdx.z;
  const int mt = blockIdx.y;
  const int nt = blockIdx.x;
  const int Ne = cnt[e];
  if (mt * 128 >= Ne) return;
  const int be = base[e];

  __shared__ __attribute__((aligned(16))) ushort_t lA[128 * 32];
  __shared__ __attribute__((aligned(16))) ushort_t lB[128 * 32];

  const int tid = threadIdx.x;
  const int lane = tid & 63;
  const int wave = tid >> 6;

  const int r1 = tid >> 2;
  const int rr1 = min(mt * 128 + r1, Ne - 1);
  const int rr2 = min(mt * 128 + r1 + 64, Ne - 1);
  const int kc = (tid & 3) ^ ((r1 >> 1) & 3);
  const ushort_t* gA1 = hbuf + (size_t)(be + rr1) * HID + kc * 8;
  const ushort_t* gA2 = hbuf + (size_t)(be + rr2) * HID + kc * 8;

  const int d0 = nt * 128;
  const ushort_t* gB1 = w2t + ((size_t)e * DIM + d0 + r1) * HID + kc * 8;
  const ushort_t* gB2 = w2t + ((size_t)e * DIM + d0 + r1 + 64) * HID + kc * 8;

  ushort_t* dA1 = lA + tid * 8;
  ushort_t* dA2 = lA + (tid + 256) * 8;
  ushort_t* dB1 = lB + tid * 8;
  ushort_t* dB2 = lB + (tid + 256) * 8;

  f32x4 c[4][4];
#pragma unroll
  for (int i = 0; i < 4; i++)
#pragma unroll
    for (int j = 0; j < 4; j++) c[i][j] = (f32x4){0.f, 0.f, 0.f, 0.f};

  const int wm = (wave >> 1) * 64;
  const int wn = (wave & 1) * 64;
  const int m = lane & 15;
  const int kq = lane >> 4;

  int aOff[4], bOff[4];
#pragma unroll
  for (int i = 0; i < 4; i++) {
    int r = wm + i * 16 + m;
    aOff[i] = (r * 4 + (kq ^ ((r >> 1) & 3))) * 8;
  }
#pragma unroll
  for (int j = 0; j < 4; j++) {
    int n = wn + j * 16 + m;
    bOff[j] = (n * 4 + (kq ^ ((n >> 1) & 3))) * 8;
  }

  for (int k0 = 0; k0 < HID; k0 += 32) {
    gl2lds16(gA1 + k0, dA1);
    gl2lds16(gA2 + k0, dA2);
    gl2lds16(gB1 + k0, dB1);
    gl2lds16(gB2 + k0, dB2);
    __syncthreads();
    bf16x8 a[4], bf[4];
#pragma unroll
    for (int i = 0; i < 4; i++) a[i] = *(const bf16x8*)(lA + aOff[i]);
#pragma unroll
    for (int j = 0; j < 4; j++) bf[j] = *(const bf16x8*)(lB + bOff[j]);
#pragma unroll
    for (int i = 0; i < 4; i++)
#pragma unroll
      for (int j = 0; j < 4; j++)
        c[i][j] = __builtin_amdgcn_mfma_f32_16x16x32_bf16(a[i], bf[j], c[i][j], 0, 0, 0);
    __syncthreads();
  }

  const int m4 = lane >> 4;
#pragma unroll
  for (int i = 0; i < 4; i++) {
    int rowg = mt * 128 + wm + i * 16 + m4 * 4;
    if (rowg >= Ne) continue;
#pragma unroll
    for (int reg = 0; reg < 4; reg++) {
      int rg = rowg + reg;
      if (rg < Ne) {
        int t = tok[e * T_TOK + rg];
        float* orow = out + (size_t)t * DIM;
#pragma unroll
        for (int j = 0; j < 4; j++) {
          int dcol = d0 + wn + j * 16 + m;
          atomicAdd(orow + dcol, c[i][j][reg]);
        }
      }
    }
  }
}

extern "C" void kernel_launch(void* const* d_in, const int* in_sizes, int n_in,
                              void* d_out, int out_size, void* d_ws, size_t ws_size,
                              hipStream_t stream) {
  (void)in_sizes; (void)n_in; (void)ws_size;
  const float* x  = (const float*)d_in[0];
  const float* Wr = (const float*)d_in[1];
  const float* W1 = (const float*)d_in[2];
  const float* W2 = (const float*)d_in[3];
  const float* W3 = (const float*)d_in[4];
  float* out = (float*)d_out;

  char* w = (char*)d_ws;
  ushort_t* xb   = (ushort_t*)w; w += (size_t)T_TOK * DIM * 2;       //   8 MB
  ushort_t* w1t  = (ushort_t*)w; w += (size_t)NE * DIM * HID * 2;    //  33.5 MB
  ushort_t* w3t  = (ushort_t*)w; w += (size_t)NE * DIM * HID * 2;    //  33.5 MB
  ushort_t* w2t  = (ushort_t*)w; w += (size_t)NE * HID * DIM * 2;    //  33.5 MB
  ushort_t* hbuf = (ushort_t*)w; w += (size_t)2 * T_TOK * HID * 2;   //  33.5 MB
  int*   tok   = (int*)w;   w += (size_t)NE * T_TOK * 4;
  float* gates = (float*)w; w += (size_t)NE * T_TOK * 4;
  int*   cnt   = (int*)w;   w += 128;
  int*   base  = (int*)w;   w += 128;

  hipMemsetAsync(d_out, 0, (size_t)out_size * sizeof(float), stream);
  hipMemsetAsync(cnt, 0, 128, stream);

  convert_x_kernel<<<T_TOK * DIM / 1024, 256, 0, stream>>>(x, xb);
  transpose_convert<<<dim3(HID / 64, DIM / 64, NE), 256, 0, stream>>>(W1, w1t, DIM, HID);
  transpose_convert<<<dim3(HID / 64, DIM / 64, NE), 256, 0, stream>>>(W3, w3t, DIM, HID);
  transpose_convert<<<dim3(DIM / 64, HID / 64, NE), 256, 0, stream>>>(W2, w2t, HID, DIM);
  router_kernel<<<T_TOK / 4, 256, 0, stream>>>(x, Wr, cnt, tok, gates);
  prefix_kernel<<<1, 64, 0, stream>>>(cnt, base);
  gemm1_kernel<<<dim3(HID / 64, 32, NE), 256, 0, stream>>>(xb, w1t, w3t, tok, gates, cnt, base, hbuf);
  gemm2_kernel<<<dim3(DIM / 128, 32, NE), 256, 0, stream>>>(hbuf, w2t, tok, cnt, base, out);
}

// Round 3
// 485.567 us; speedup vs baseline: 1.1458x; 1.1007x over previous
//
#include <hip/hip_runtime.h>
#include <hip/hip_bf16.h>
#include <stdint.h>

#define T_TOK 4096
#define DIM   1024
#define HID   2048
#define NE    8

typedef unsigned short ushort_t;
typedef __attribute__((ext_vector_type(8))) short bf16x8;
typedef __attribute__((ext_vector_type(4))) float f32x4;

__device__ __forceinline__ unsigned short f2bf(float f) {
  unsigned u = __float_as_uint(f);
  unsigned r = (u + 0x7fffu + ((u >> 16) & 1u)) >> 16;
  return (unsigned short)r;
}

__device__ __forceinline__ void gl2lds16(const ushort_t* g, ushort_t* l) {
  void* gv = (void*)g;
  __builtin_amdgcn_global_load_lds((__attribute__((address_space(1))) void*)gv,
                                   (__attribute__((address_space(3))) void*)l,
                                   16, 0, 0);
}

// ================= fused prep =================
// blocks [0,12288): transpose+convert W1/W3/W2 -> bf16 k-contiguous
// blocks [12288,16384): x fp32 -> bf16
// blocks [16384,17408): router (4 tokens/block)
// blocks [17408,18432): zero d_out
__global__ __launch_bounds__(256)
void prep_kernel(const float* __restrict__ x, const float* __restrict__ Wr,
                 const float* __restrict__ W1, const float* __restrict__ W2,
                 const float* __restrict__ W3,
                 ushort_t* __restrict__ xb,
                 ushort_t* __restrict__ w1t, ushort_t* __restrict__ w3t,
                 ushort_t* __restrict__ w2t,
                 int* __restrict__ cnt, int* __restrict__ tok,
                 float* __restrict__ gate, float* __restrict__ out) {
  const int b = blockIdx.x;
  const int tid = threadIdx.x;
  __shared__ float lds[64][65];

  if (b < 12288) {
    // ---- transpose+convert: src fp32 [R][C] -> dst bf16 [C][R] ----
    const float* src; ushort_t* dst; int R, C, cx, ry;
    const int which = b >> 12;
    const int id = b & 4095;
    const int e = id >> 9, rem = id & 511;
    if (which == 0)      { src = W1; dst = w1t; R = DIM; C = HID; cx = rem & 31; ry = rem >> 5; }
    else if (which == 1) { src = W3; dst = w3t; R = DIM; C = HID; cx = rem & 31; ry = rem >> 5; }
    else                 { src = W2; dst = w2t; R = HID; C = DIM; cx = rem & 15; ry = rem >> 4; }
    const float* s = src + (size_t)e * R * C;
    ushort_t* d = dst + (size_t)e * R * C;
    const int c0 = cx * 64, r0 = ry * 64;
#pragma unroll
    for (int p = 0; p < 4; p++) {
      int idx = p * 256 + tid;
      int r = idx >> 4, c4 = idx & 15;
      float4 v = *(const float4*)(s + (size_t)(r0 + r) * C + c0 + c4 * 4);
      lds[r][c4 * 4 + 0] = v.x; lds[r][c4 * 4 + 1] = v.y;
      lds[r][c4 * 4 + 2] = v.z; lds[r][c4 * 4 + 3] = v.w;
    }
    __syncthreads();
#pragma unroll
    for (int p = 0; p < 4; p++) {
      int idx = p * 256 + tid;
      int cc = idx >> 4, r4 = idx & 15;
      ushort4 o;
      o.x = f2bf(lds[r4 * 4 + 0][cc]);
      o.y = f2bf(lds[r4 * 4 + 1][cc]);
      o.z = f2bf(lds[r4 * 4 + 2][cc]);
      o.w = f2bf(lds[r4 * 4 + 3][cc]);
      *(ushort4*)(d + (size_t)(c0 + cc) * R + r0 + r4 * 4) = o;
    }
  } else if (b < 16384) {
    // ---- x fp32 -> bf16 ----
    int i = (b - 12288) * 256 + tid;
    float4 v = ((const float4*)x)[i];
    ushort4 o;
    o.x = f2bf(v.x); o.y = f2bf(v.y); o.z = f2bf(v.z); o.w = f2bf(v.w);
    ((ushort4*)xb)[i] = o;
  } else if (b < 17408) {
    // ---- router ----
    const int wave = tid >> 6;
    const int lane = tid & 63;
    const int t = (b - 16384) * 4 + wave;
    float acc[NE];
#pragma unroll
    for (int e = 0; e < NE; e++) acc[e] = 0.f;
    const float* xr = x + (size_t)t * DIM;
    for (int dd = lane; dd < DIM; dd += 64) {
      float xv = xr[dd];
      const float* wr = Wr + (size_t)dd * NE;
#pragma unroll
      for (int e = 0; e < NE; e++) acc[e] += xv * wr[e];
    }
#pragma unroll
    for (int off = 32; off >= 1; off >>= 1) {
#pragma unroll
      for (int e = 0; e < NE; e++) acc[e] += __shfl_xor(acc[e], off, 64);
    }
    if (lane == 0) {
      int i1 = 0;
#pragma unroll
      for (int e = 1; e < NE; e++) if (acc[e] > acc[i1]) i1 = e;
      int i2 = (i1 == 0) ? 1 : 0;
#pragma unroll
      for (int e = 0; e < NE; e++) {
        if (e == i1) continue;
        if (acc[e] > acc[i2]) i2 = e;
      }
      float r = expf(acc[i2] - acc[i1]);
      float g1 = 1.f / (1.f + r);
      float g2 = 1.f - g1;
      int p;
      p = atomicAdd(&cnt[i1], 1); tok[i1 * T_TOK + p] = t; gate[i1 * T_TOK + p] = g1;
      p = atomicAdd(&cnt[i2], 1); tok[i2 * T_TOK + p] = t; gate[i2 * T_TOK + p] = g2;
    }
  } else {
    // ---- zero out ----
    int base_i = (b - 17408) * 1024;
    float4 z = {0.f, 0.f, 0.f, 0.f};
#pragma unroll
    for (int it = 0; it < 4; it++) ((float4*)out)[base_i + it * 256 + tid] = z;
  }
}

// ================= GEMM1: h = gate*silu(x@W1)*(x@W3), BK=64 =================
// 128m x 64h tile; per wave 64x32 for BOTH W1,W3; 32 MFMA per barrier
__global__ __launch_bounds__(256, 3)
void gemm1_kernel(const ushort_t* __restrict__ xb,
                  const ushort_t* __restrict__ w1t,
                  const ushort_t* __restrict__ w3t,
                  const int* __restrict__ tok,
                  const float* __restrict__ gates,
                  const int* __restrict__ cnt,
                  ushort_t* __restrict__ hbuf) {
  const int e = blockIdx.z, mt = blockIdx.y, nt = blockIdx.x;
  const int Ne = cnt[e];
  if (mt * 128 >= Ne) return;
  int be = 0;
#pragma unroll
  for (int i = 0; i < NE; i++) be += (i < e) ? cnt[i] : 0;

  __shared__ __attribute__((aligned(16))) ushort_t lA[128 * 64];
  __shared__ __attribute__((aligned(16))) ushort_t lB1[64 * 64];
  __shared__ __attribute__((aligned(16))) ushort_t lB3[64 * 64];

  const int tid = threadIdx.x, lane = tid & 63, wave = tid >> 6;
  // staged chunk: LDS slot = row*8 + pos holds global chunk pos^(row&7)
  const int kco = ((tid & 7) ^ ((tid >> 3) & 7)) * 8;

  const ushort_t* pA[4];
#pragma unroll
  for (int it = 0; it < 4; it++) {
    int rowg = mt * 128 + it * 32 + (tid >> 3);
    int t = (rowg < Ne) ? tok[e * T_TOK + rowg] : 0;
    pA[it] = xb + (size_t)t * DIM + kco;
  }
  const int h0 = nt * 64;
  const ushort_t* pB1[2];
  const ushort_t* pB3[2];
#pragma unroll
  for (int it = 0; it < 2; it++) {
    int row = h0 + it * 32 + (tid >> 3);
    pB1[it] = w1t + ((size_t)e * HID + row) * DIM + kco;
    pB3[it] = w3t + ((size_t)e * HID + row) * DIM + kco;
  }

  f32x4 c1[4][2], c3[4][2];
#pragma unroll
  for (int i = 0; i < 4; i++)
#pragma unroll
    for (int j = 0; j < 2; j++) {
      c1[i][j] = (f32x4){0.f, 0.f, 0.f, 0.f};
      c3[i][j] = (f32x4){0.f, 0.f, 0.f, 0.f};
    }

  const int wm = (wave >> 1) * 64, wn = (wave & 1) * 32;
  const int m = lane & 15, kq = lane >> 4;
  int aRow[4], bRow[2], cSlot[2];
#pragma unroll
  for (int i = 0; i < 4; i++) aRow[i] = (wm + i * 16 + m) * 64;
#pragma unroll
  for (int j = 0; j < 2; j++) bRow[j] = (wn + j * 16 + m) * 64;
#pragma unroll
  for (int u = 0; u < 2; u++) cSlot[u] = ((u * 4 + kq) ^ (m & 7)) * 8;

  for (int k0 = 0; k0 < DIM; k0 += 64) {
#pragma unroll
    for (int it = 0; it < 4; it++) gl2lds16(pA[it] + k0, lA + (it * 256 + tid) * 8);
#pragma unroll
    for (int it = 0; it < 2; it++) {
      gl2lds16(pB1[it] + k0, lB1 + (it * 256 + tid) * 8);
      gl2lds16(pB3[it] + k0, lB3 + (it * 256 + tid) * 8);
    }
    __syncthreads();
#pragma unroll
    for (int u = 0; u < 2; u++) {
      bf16x8 a[4], b1f[2], b3f[2];
#pragma unroll
      for (int i = 0; i < 4; i++) a[i] = *(const bf16x8*)(lA + aRow[i] + cSlot[u]);
#pragma unroll
      for (int j = 0; j < 2; j++) {
        b1f[j] = *(const bf16x8*)(lB1 + bRow[j] + cSlot[u]);
        b3f[j] = *(const bf16x8*)(lB3 + bRow[j] + cSlot[u]);
      }
#pragma unroll
      for (int i = 0; i < 4; i++)
#pragma unroll
        for (int j = 0; j < 2; j++) {
          c1[i][j] = __builtin_amdgcn_mfma_f32_16x16x32_bf16(a[i], b1f[j], c1[i][j], 0, 0, 0);
          c3[i][j] = __builtin_amdgcn_mfma_f32_16x16x32_bf16(a[i], b3f[j], c3[i][j], 0, 0, 0);
        }
    }
    __syncthreads();
  }

  const int m4 = lane >> 4;
#pragma unroll
  for (int i = 0; i < 4; i++) {
#pragma unroll
    for (int j = 0; j < 2; j++) {
      int hcol = h0 + wn + j * 16 + m;
#pragma unroll
      for (int reg = 0; reg < 4; reg++) {
        int rowg = mt * 128 + wm + i * 16 + m4 * 4 + reg;
        if (rowg < Ne) {
          float v1 = c1[i][j][reg];
          float v3 = c3[i][j][reg];
          float g = gates[e * T_TOK + rowg];
          float hv = g * (v1 / (1.f + expf(-v1))) * v3;
          hbuf[(size_t)(be + rowg) * HID + hcol] = f2bf(hv);
        }
      }
    }
  }
}

// ================= GEMM2: out[tok] += h @ W2, BK=64 =================
// 128m x 128d tile; per wave 64x64; 32 MFMA per barrier
__global__ __launch_bounds__(256, 3)
void gemm2_kernel(const ushort_t* __restrict__ hbuf,
                  const ushort_t* __restrict__ w2t,
                  const int* __restrict__ tok,
                  const int* __restrict__ cnt,
                  float* __restrict__ out) {
  const int e = blockIdx.z, mt = blockIdx.y, nt = blockIdx.x;
  const int Ne = cnt[e];
  if (mt * 128 >= Ne) return;
  int be = 0;
#pragma unroll
  for (int i = 0; i < NE; i++) be += (i < e) ? cnt[i] : 0;

  __shared__ __attribute__((aligned(16))) ushort_t lA[128 * 64];
  __shared__ __attribute__((aligned(16))) ushort_t lB[128 * 64];

  const int tid = threadIdx.x, lane = tid & 63, wave = tid >> 6;
  const int kco = ((tid & 7) ^ ((tid >> 3) & 7)) * 8;

  const ushort_t* pA[4];
#pragma unroll
  for (int it = 0; it < 4; it++) {
    int rr = min(mt * 128 + it * 32 + (tid >> 3), Ne - 1);
    pA[it] = hbuf + (size_t)(be + rr) * HID + kco;
  }
  const int d0 = nt * 128;
  const ushort_t* pB[4];
#pragma unroll
  for (int it = 0; it < 4; it++) {
    int row = d0 + it * 32 + (tid >> 3);
    pB[it] = w2t + ((size_t)e * DIM + row) * HID + kco;
  }

  f32x4 c[4][4];
#pragma unroll
  for (int i = 0; i < 4; i++)
#pragma unroll
    for (int j = 0; j < 4; j++) c[i][j] = (f32x4){0.f, 0.f, 0.f, 0.f};

  const int wm = (wave >> 1) * 64, wn = (wave & 1) * 64;
  const int m = lane & 15, kq = lane >> 4;
  int aRow[4], bRow[4], cSlot[2];
#pragma unroll
  for (int i = 0; i < 4; i++) aRow[i] = (wm + i * 16 + m) * 64;
#pragma unroll
  for (int j = 0; j < 4; j++) bRow[j] = (wn + j * 16 + m) * 64;
#pragma unroll
  for (int u = 0; u < 2; u++) cSlot[u] = ((u * 4 + kq) ^ (m & 7)) * 8;

  for (int k0 = 0; k0 < HID; k0 += 64) {
#pragma unroll
    for (int it = 0; it < 4; it++) {
      gl2lds16(pA[it] + k0, lA + (it * 256 + tid) * 8);
      gl2lds16(pB[it] + k0, lB + (it * 256 + tid) * 8);
    }
    __syncthreads();
#pragma unroll
    for (int u = 0; u < 2; u++) {
      bf16x8 a[4], bf[4];
#pragma unroll
      for (int i = 0; i < 4; i++) a[i] = *(const bf16x8*)(lA + aRow[i] + cSlot[u]);
#pragma unroll
      for (int j = 0; j < 4; j++) bf[j] = *(const bf16x8*)(lB + bRow[j] + cSlot[u]);
#pragma unroll
      for (int i = 0; i < 4; i++)
#pragma unroll
        for (int j = 0; j < 4; j++)
          c[i][j] = __builtin_amdgcn_mfma_f32_16x16x32_bf16(a[i], bf[j], c[i][j], 0, 0, 0);
    }
    __syncthreads();
  }

  const int m4 = lane >> 4;
#pragma unroll
  for (int i = 0; i < 4; i++) {
    int rowg = mt * 128 + wm + i * 16 + m4 * 4;
    if (rowg >= Ne) continue;
#pragma unroll
    for (int reg = 0; reg < 4; reg++) {
      int rg = rowg + reg;
      if (rg < Ne) {
        int t = tok[e * T_TOK + rg];
        float* orow = out + (size_t)t * DIM;
#pragma unroll
        for (int j = 0; j < 4; j++) {
          int dcol = d0 + wn + j * 16 + m;
          atomicAdd(orow + dcol, c[i][j][reg]);
        }
      }
    }
  }
}

extern "C" void kernel_launch(void* const* d_in, const int* in_sizes, int n_in,
                              void* d_out, int out_size, void* d_ws, size_t ws_size,
                              hipStream_t stream) {
  (void)in_sizes; (void)n_in; (void)ws_size; (void)out_size;
  const float* x  = (const float*)d_in[0];
  const float* Wr = (const float*)d_in[1];
  const float* W1 = (const float*)d_in[2];
  const float* W2 = (const float*)d_in[3];
  const float* W3 = (const float*)d_in[4];
  float* out = (float*)d_out;

  char* w = (char*)d_ws;
  ushort_t* xb   = (ushort_t*)w; w += (size_t)T_TOK * DIM * 2;
  ushort_t* w1t  = (ushort_t*)w; w += (size_t)NE * DIM * HID * 2;
  ushort_t* w3t  = (ushort_t*)w; w += (size_t)NE * DIM * HID * 2;
  ushort_t* w2t  = (ushort_t*)w; w += (size_t)NE * HID * DIM * 2;
  ushort_t* hbuf = (ushort_t*)w; w += (size_t)2 * T_TOK * HID * 2;
  int*   tok   = (int*)w;   w += (size_t)NE * T_TOK * 4;
  float* gates = (float*)w; w += (size_t)NE * T_TOK * 4;
  int*   cnt   = (int*)w;   w += 128;

  hipMemsetAsync(cnt, 0, 128, stream);
  prep_kernel<<<18432, 256, 0, stream>>>(x, Wr, W1, W2, W3, xb, w1t, w3t, w2t,
                                         cnt, tok, gates, out);
  gemm1_kernel<<<dim3(HID / 64, 32, NE), 256, 0, stream>>>(xb, w1t, w3t, tok, gates, cnt, hbuf);
  gemm2_kernel<<<dim3(DIM / 128, 32, NE), 256, 0, stream>>>(hbuf, w2t, tok, cnt, out);
}

// Round 4
// 414.044 us; speedup vs baseline: 1.3437x; 1.1727x over previous
//
#include <hip/hip_runtime.h>
#include <hip/hip_bf16.h>
#include <stdint.h>

#define T_TOK 4096
#define DIM   1024
#define HID   2048
#define NE    8

typedef unsigned short ushort_t;
typedef __attribute__((ext_vector_type(8))) short bf16x8;
typedef __attribute__((ext_vector_type(4))) float f32x4;

__device__ __forceinline__ unsigned short f2bf(float f) {
  unsigned u = __float_as_uint(f);
  unsigned r = (u + 0x7fffu + ((u >> 16) & 1u)) >> 16;
  return (unsigned short)r;
}

__device__ __forceinline__ void gl2lds16(const ushort_t* g, ushort_t* l) {
  void* gv = (void*)g;
  __builtin_amdgcn_global_load_lds((__attribute__((address_space(1))) void*)gv,
                                   (__attribute__((address_space(3))) void*)l,
                                   16, 0, 0);
}

// ================= fused prep =================
// blocks [0,12288): transpose+convert W1/W3/W2 -> bf16 k-contiguous
// blocks [12288,13312): router compute (no atomics) + x fp32->bf16 (4 tokens/block)
// blocks [13312,14336): zero d_out
__global__ __launch_bounds__(256)
void prep_kernel(const float* __restrict__ x, const float* __restrict__ Wr,
                 const float* __restrict__ W1, const float* __restrict__ W2,
                 const float* __restrict__ W3,
                 ushort_t* __restrict__ xb,
                 ushort_t* __restrict__ w1t, ushort_t* __restrict__ w3t,
                 ushort_t* __restrict__ w2t,
                 int* __restrict__ eidx, float2* __restrict__ gpair,
                 float* __restrict__ out) {
  const int b = blockIdx.x;
  const int tid = threadIdx.x;
  __shared__ float lds[64][65];

  if (b < 12288) {
    // ---- transpose+convert: src fp32 [R][C] -> dst bf16 [C][R] ----
    const float* src; ushort_t* dst; int R, C, cx, ry;
    const int which = b >> 12;
    const int id = b & 4095;
    const int e = id >> 9, rem = id & 511;
    if (which == 0)      { src = W1; dst = w1t; R = DIM; C = HID; cx = rem & 31; ry = rem >> 5; }
    else if (which == 1) { src = W3; dst = w3t; R = DIM; C = HID; cx = rem & 31; ry = rem >> 5; }
    else                 { src = W2; dst = w2t; R = HID; C = DIM; cx = rem & 15; ry = rem >> 4; }
    const float* s = src + (size_t)e * R * C;
    ushort_t* d = dst + (size_t)e * R * C;
    const int c0 = cx * 64, r0 = ry * 64;
#pragma unroll
    for (int p = 0; p < 4; p++) {
      int idx = p * 256 + tid;
      int r = idx >> 4, c4 = idx & 15;
      float4 v = *(const float4*)(s + (size_t)(r0 + r) * C + c0 + c4 * 4);
      lds[r][c4 * 4 + 0] = v.x; lds[r][c4 * 4 + 1] = v.y;
      lds[r][c4 * 4 + 2] = v.z; lds[r][c4 * 4 + 3] = v.w;
    }
    __syncthreads();
#pragma unroll
    for (int p = 0; p < 4; p++) {
      int idx = p * 256 + tid;
      int cc = idx >> 4, r4 = idx & 15;
      ushort4 o;
      o.x = f2bf(lds[r4 * 4 + 0][cc]);
      o.y = f2bf(lds[r4 * 4 + 1][cc]);
      o.z = f2bf(lds[r4 * 4 + 2][cc]);
      o.w = f2bf(lds[r4 * 4 + 3][cc]);
      *(ushort4*)(d + (size_t)(c0 + cc) * R + r0 + r4 * 4) = o;
    }
  } else if (b < 13312) {
    // ---- router compute + x convert: one token per wave ----
    const int wave = tid >> 6;
    const int lane = tid & 63;
    const int t = (b - 12288) * 4 + wave;
    const float* xr = x + (size_t)t * DIM;
    ushort_t* xbr = xb + (size_t)t * DIM;
    float acc[NE];
#pragma unroll
    for (int e = 0; e < NE; e++) acc[e] = 0.f;
#pragma unroll
    for (int it = 0; it < 4; it++) {
      int d4 = it * 64 + lane;                 // float4 index within the row
      float4 v = ((const float4*)xr)[d4];
      ushort4 o;
      o.x = f2bf(v.x); o.y = f2bf(v.y); o.z = f2bf(v.z); o.w = f2bf(v.w);
      ((ushort4*)xbr)[d4] = o;
      const float* wr = Wr + (size_t)d4 * 4 * NE;
      float c[4] = {v.x, v.y, v.z, v.w};
#pragma unroll
      for (int cc = 0; cc < 4; cc++)
#pragma unroll
        for (int e = 0; e < NE; e++) acc[e] += c[cc] * wr[cc * NE + e];
    }
#pragma unroll
    for (int off = 32; off >= 1; off >>= 1) {
#pragma unroll
      for (int e = 0; e < NE; e++) acc[e] += __shfl_xor(acc[e], off, 64);
    }
    if (lane == 0) {
      int i1 = 0;
#pragma unroll
      for (int e = 1; e < NE; e++) if (acc[e] > acc[i1]) i1 = e;
      int i2 = (i1 == 0) ? 1 : 0;
#pragma unroll
      for (int e = 0; e < NE; e++) {
        if (e == i1) continue;
        if (acc[e] > acc[i2]) i2 = e;
      }
      float r = expf(acc[i2] - acc[i1]);       // p2/p1
      float g1 = 1.f / (1.f + r);
      eidx[t] = i1 | (i2 << 8);
      gpair[t] = make_float2(g1, 1.f - g1);
    }
  } else {
    // ---- zero out ----
    int base_i = (b - 13312) * 1024;
    float4 z = {0.f, 0.f, 0.f, 0.f};
#pragma unroll
    for (int it = 0; it < 4; it++) ((float4*)out)[base_i + it * 256 + tid] = z;
  }
}

// ================= compaction: LDS atomics, one block =================
__global__ __launch_bounds__(1024)
void compact_kernel(const int* __restrict__ eidx, const float2* __restrict__ gpair,
                    int* __restrict__ cnt, int* __restrict__ tok,
                    float* __restrict__ gate) {
  __shared__ int lcnt[NE];
  const int tid = threadIdx.x;
  if (tid < NE) lcnt[tid] = 0;
  __syncthreads();
  for (int t = tid; t < T_TOK; t += 1024) {
    int pk = eidx[t];
    int i1 = pk & 0xff, i2 = (pk >> 8) & 0xff;
    float2 g = gpair[t];
    int p1 = atomicAdd(&lcnt[i1], 1);
    tok[i1 * T_TOK + p1] = t; gate[i1 * T_TOK + p1] = g.x;
    int p2 = atomicAdd(&lcnt[i2], 1);
    tok[i2 * T_TOK + p2] = t; gate[i2 * T_TOK + p2] = g.y;
  }
  __syncthreads();
  if (tid < NE) cnt[tid] = lcnt[tid];
}

// ================= GEMM1: h = gate*silu(x@W1)*(x@W3), BK=64 =================
// 128m x 64h tile; per wave 64x32 for BOTH W1,W3; 32 MFMA per barrier
__global__ __launch_bounds__(256, 3)
void gemm1_kernel(const ushort_t* __restrict__ xb,
                  const ushort_t* __restrict__ w1t,
                  const ushort_t* __restrict__ w3t,
                  const int* __restrict__ tok,
                  const float* __restrict__ gates,
                  const int* __restrict__ cnt,
                  ushort_t* __restrict__ hbuf) {
  const int e = blockIdx.z, mt = blockIdx.y, nt = blockIdx.x;
  const int Ne = cnt[e];
  if (mt * 128 >= Ne) return;
  int be = 0;
#pragma unroll
  for (int i = 0; i < NE; i++) be += (i < e) ? cnt[i] : 0;

  __shared__ __attribute__((aligned(16))) ushort_t lA[128 * 64];
  __shared__ __attribute__((aligned(16))) ushort_t lB1[64 * 64];
  __shared__ __attribute__((aligned(16))) ushort_t lB3[64 * 64];

  const int tid = threadIdx.x, lane = tid & 63, wave = tid >> 6;
  const int kco = ((tid & 7) ^ ((tid >> 3) & 7)) * 8;

  const ushort_t* pA[4];
#pragma unroll
  for (int it = 0; it < 4; it++) {
    int rowg = mt * 128 + it * 32 + (tid >> 3);
    int t = (rowg < Ne) ? tok[e * T_TOK + rowg] : 0;
    pA[it] = xb + (size_t)t * DIM + kco;
  }
  const int h0 = nt * 64;
  const ushort_t* pB1[2];
  const ushort_t* pB3[2];
#pragma unroll
  for (int it = 0; it < 2; it++) {
    int row = h0 + it * 32 + (tid >> 3);
    pB1[it] = w1t + ((size_t)e * HID + row) * DIM + kco;
    pB3[it] = w3t + ((size_t)e * HID + row) * DIM + kco;
  }

  f32x4 c1[4][2], c3[4][2];
#pragma unroll
  for (int i = 0; i < 4; i++)
#pragma unroll
    for (int j = 0; j < 2; j++) {
      c1[i][j] = (f32x4){0.f, 0.f, 0.f, 0.f};
      c3[i][j] = (f32x4){0.f, 0.f, 0.f, 0.f};
    }

  const int wm = (wave >> 1) * 64, wn = (wave & 1) * 32;
  const int m = lane & 15, kq = lane >> 4;
  int aRow[4], bRow[2], cSlot[2];
#pragma unroll
  for (int i = 0; i < 4; i++) aRow[i] = (wm + i * 16 + m) * 64;
#pragma unroll
  for (int j = 0; j < 2; j++) bRow[j] = (wn + j * 16 + m) * 64;
#pragma unroll
  for (int u = 0; u < 2; u++) cSlot[u] = ((u * 4 + kq) ^ (m & 7)) * 8;

  for (int k0 = 0; k0 < DIM; k0 += 64) {
#pragma unroll
    for (int it = 0; it < 4; it++) gl2lds16(pA[it] + k0, lA + (it * 256 + tid) * 8);
#pragma unroll
    for (int it = 0; it < 2; it++) {
      gl2lds16(pB1[it] + k0, lB1 + (it * 256 + tid) * 8);
      gl2lds16(pB3[it] + k0, lB3 + (it * 256 + tid) * 8);
    }
    __syncthreads();
#pragma unroll
    for (int u = 0; u < 2; u++) {
      bf16x8 a[4], b1f[2], b3f[2];
#pragma unroll
      for (int i = 0; i < 4; i++) a[i] = *(const bf16x8*)(lA + aRow[i] + cSlot[u]);
#pragma unroll
      for (int j = 0; j < 2; j++) {
        b1f[j] = *(const bf16x8*)(lB1 + bRow[j] + cSlot[u]);
        b3f[j] = *(const bf16x8*)(lB3 + bRow[j] + cSlot[u]);
      }
#pragma unroll
      for (int i = 0; i < 4; i++)
#pragma unroll
        for (int j = 0; j < 2; j++) {
          c1[i][j] = __builtin_amdgcn_mfma_f32_16x16x32_bf16(a[i], b1f[j], c1[i][j], 0, 0, 0);
          c3[i][j] = __builtin_amdgcn_mfma_f32_16x16x32_bf16(a[i], b3f[j], c3[i][j], 0, 0, 0);
        }
    }
    __syncthreads();
  }

  const int m4 = lane >> 4;
#pragma unroll
  for (int i = 0; i < 4; i++) {
#pragma unroll
    for (int j = 0; j < 2; j++) {
      int hcol = h0 + wn + j * 16 + m;
#pragma unroll
      for (int reg = 0; reg < 4; reg++) {
        int rowg = mt * 128 + wm + i * 16 + m4 * 4 + reg;
        if (rowg < Ne) {
          float v1 = c1[i][j][reg];
          float v3 = c3[i][j][reg];
          float g = gates[e * T_TOK + rowg];
          float hv = g * (v1 / (1.f + expf(-v1))) * v3;
          hbuf[(size_t)(be + rowg) * HID + hcol] = f2bf(hv);
        }
      }
    }
  }
}

// ================= GEMM2: out[tok] += h @ W2, BK=64 =================
// 128m x 128d tile; per wave 64x64; 32 MFMA per barrier
__global__ __launch_bounds__(256, 3)
void gemm2_kernel(const ushort_t* __restrict__ hbuf,
                  const ushort_t* __restrict__ w2t,
                  const int* __restrict__ tok,
                  const int* __restrict__ cnt,
                  float* __restrict__ out) {
  const int e = blockIdx.z, mt = blockIdx.y, nt = blockIdx.x;
  const int Ne = cnt[e];
  if (mt * 128 >= Ne) return;
  int be = 0;
#pragma unroll
  for (int i = 0; i < NE; i++) be += (i < e) ? cnt[i] : 0;

  __shared__ __attribute__((aligned(16))) ushort_t lA[128 * 64];
  __shared__ __attribute__((aligned(16))) ushort_t lB[128 * 64];

  const int tid = threadIdx.x, lane = tid & 63, wave = tid >> 6;
  const int kco = ((tid & 7) ^ ((tid >> 3) & 7)) * 8;

  const ushort_t* pA[4];
#pragma unroll
  for (int it = 0; it < 4; it++) {
    int rr = min(mt * 128 + it * 32 + (tid >> 3), Ne - 1);
    pA[it] = hbuf + (size_t)(be + rr) * HID + kco;
  }
  const int d0 = nt * 128;
  const ushort_t* pB[4];
#pragma unroll
  for (int it = 0; it < 4; it++) {
    int row = d0 + it * 32 + (tid >> 3);
    pB[it] = w2t + ((size_t)e * DIM + row) * HID + kco;
  }

  f32x4 c[4][4];
#pragma unroll
  for (int i = 0; i < 4; i++)
#pragma unroll
    for (int j = 0; j < 4; j++) c[i][j] = (f32x4){0.f, 0.f, 0.f, 0.f};

  const int wm = (wave >> 1) * 64, wn = (wave & 1) * 64;
  const int m = lane & 15, kq = lane >> 4;
  int aRow[4], bRow[4], cSlot[2];
#pragma unroll
  for (int i = 0; i < 4; i++) aRow[i] = (wm + i * 16 + m) * 64;
#pragma unroll
  for (int j = 0; j < 4; j++) bRow[j] = (wn + j * 16 + m) * 64;
#pragma unroll
  for (int u = 0; u < 2; u++) cSlot[u] = ((u * 4 + kq) ^ (m & 7)) * 8;

  for (int k0 = 0; k0 < HID; k0 += 64) {
#pragma unroll
    for (int it = 0; it < 4; it++) {
      gl2lds16(pA[it] + k0, lA + (it * 256 + tid) * 8);
      gl2lds16(pB[it] + k0, lB + (it * 256 + tid) * 8);
    }
    __syncthreads();
#pragma unroll
    for (int u = 0; u < 2; u++) {
      bf16x8 a[4], bf[4];
#pragma unroll
      for (int i = 0; i < 4; i++) a[i] = *(const bf16x8*)(lA + aRow[i] + cSlot[u]);
#pragma unroll
      for (int j = 0; j < 4; j++) bf[j] = *(const bf16x8*)(lB + bRow[j] + cSlot[u]);
#pragma unroll
      for (int i = 0; i < 4; i++)
#pragma unroll
        for (int j = 0; j < 4; j++)
          c[i][j] = __builtin_amdgcn_mfma_f32_16x16x32_bf16(a[i], bf[j], c[i][j], 0, 0, 0);
    }
    __syncthreads();
  }

  const int m4 = lane >> 4;
#pragma unroll
  for (int i = 0; i < 4; i++) {
    int rowg = mt * 128 + wm + i * 16 + m4 * 4;
    if (rowg >= Ne) continue;
#pragma unroll
    for (int reg = 0; reg < 4; reg++) {
      int rg = rowg + reg;
      if (rg < Ne) {
        int t = tok[e * T_TOK + rg];
        float* orow = out + (size_t)t * DIM;
#pragma unroll
        for (int j = 0; j < 4; j++) {
          int dcol = d0 + wn + j * 16 + m;
          atomicAdd(orow + dcol, c[i][j][reg]);
        }
      }
    }
  }
}

extern "C" void kernel_launch(void* const* d_in, const int* in_sizes, int n_in,
                              void* d_out, int out_size, void* d_ws, size_t ws_size,
                              hipStream_t stream) {
  (void)in_sizes; (void)n_in; (void)ws_size; (void)out_size;
  const float* x  = (const float*)d_in[0];
  const float* Wr = (const float*)d_in[1];
  const float* W1 = (const float*)d_in[2];
  const float* W2 = (const float*)d_in[3];
  const float* W3 = (const float*)d_in[4];
  float* out = (float*)d_out;

  char* w = (char*)d_ws;
  ushort_t* xb   = (ushort_t*)w; w += (size_t)T_TOK * DIM * 2;
  ushort_t* w1t  = (ushort_t*)w; w += (size_t)NE * DIM * HID * 2;
  ushort_t* w3t  = (ushort_t*)w; w += (size_t)NE * DIM * HID * 2;
  ushort_t* w2t  = (ushort_t*)w; w += (size_t)NE * HID * DIM * 2;
  ushort_t* hbuf = (ushort_t*)w; w += (size_t)2 * T_TOK * HID * 2;
  int*    tok   = (int*)w;    w += (size_t)NE * T_TOK * 4;
  float*  gates = (float*)w;  w += (size_t)NE * T_TOK * 4;
  int*    eidx  = (int*)w;    w += (size_t)T_TOK * 4;
  float2* gpair = (float2*)w; w += (size_t)T_TOK * 8;
  int*    cnt   = (int*)w;    w += 128;

  prep_kernel<<<14336, 256, 0, stream>>>(x, Wr, W1, W2, W3, xb, w1t, w3t, w2t,
                                         eidx, gpair, out);
  compact_kernel<<<1, 1024, 0, stream>>>(eidx, gpair, cnt, tok, gates);
  gemm1_kernel<<<dim3(HID / 64, 32, NE), 256, 0, stream>>>(xb, w1t, w3t, tok, gates, cnt, hbuf);
  gemm2_kernel<<<dim3(DIM / 128, 32, NE), 256, 0, stream>>>(hbuf, w2t, tok, cnt, out);
}